// Round 18
// baseline (44.287 us; speedup 1.0000x reference)
//
#include <hip/hip_runtime.h>
#include <math.h>

#define ALPHA 0.2f
#define MAXK 10

typedef _Float16 half8 __attribute__((ext_vector_type(8)));
typedef _Float16 half4 __attribute__((ext_vector_type(4)));
typedef float f32x4 __attribute__((ext_vector_type(4)));

__device__ __forceinline__ void gload_lds16(const void* g, void* l) {
    __builtin_amdgcn_global_load_lds(
        (const __attribute__((address_space(1))) unsigned int*)g,
        (__attribute__((address_space(3))) unsigned int*)l, 16, 0, 0);
}

__device__ __forceinline__ float dot4(float4 a, float4 b) {
    return a.x * b.x + a.y * b.y + a.z * b.z + a.w * b.w;
}

// ---------------- proven bodies ----------------

// R9-proven aggregate row body. smem: needs 176B scratch.
__device__ __forceinline__ void mid_body(
    int i, int tid, const float* __restrict__ feat, const float* __restrict__ embed,
    const int* __restrict__ nidx, const float* __restrict__ wa,
    _Float16* __restrict__ agg, int F, char* smem) {
    const int f = tid * 4;
    int idx[MAXK];
    bool dup[MAXK];
    #pragma unroll
    for (int k = 0; k < MAXK; k++) idx[k] = nidx[i * MAXK + k];
    #pragma unroll
    for (int k = 0; k < MAXK; k++) {
        bool d = false;
        #pragma unroll
        for (int p = 0; p < MAXK; p++)
            if (p < k) d |= (idx[p] == idx[k]);
        dup[k] = d;
    }
    float4 wa1 = *(const float4*)&wa[f];
    float4 wa2 = *(const float4*)&wa[F + f];
    float4 fv  = *(const float4*)&feat[(size_t)i * F + f];
    float a1p = dot4(fv, wa1);
    float4 rv[MAXK];
    float a2p[MAXK];
    #pragma unroll
    for (int k = 0; k < MAXK; k++) {
        rv[k] = *(const float4*)&embed[(size_t)idx[k] * F + f];
        a2p[k] = dot4(rv[k], wa2);
    }
    #pragma unroll
    for (int off = 32; off; off >>= 1) {
        a1p += __shfl_down(a1p, off);
        #pragma unroll
        for (int k = 0; k < MAXK; k++) a2p[k] += __shfl_down(a2p[k], off);
    }
    float (*red)[4] = (float(*)[4])smem;
    const int w = tid >> 6, l = tid & 63;
    if (l == 0) {
        red[0][w] = a1p;
        #pragma unroll
        for (int k = 0; k < MAXK; k++) red[k + 1][w] = a2p[k];
    }
    __syncthreads();
    float s1 = red[0][0] + red[0][1] + red[0][2] + red[0][3];
    float sc[MAXK];
    float m = -INFINITY;
    #pragma unroll
    for (int k = 0; k < MAXK; k++) {
        float v = s1 + red[k + 1][0] + red[k + 1][1] + red[k + 1][2] + red[k + 1][3];
        v = v > 0.f ? v : ALPHA * v;
        sc[k] = v;
        if (!dup[k]) m = fmaxf(m, v);
    }
    float sum = 0.f;
    #pragma unroll
    for (int k = 0; k < MAXK; k++) {
        sc[k] = dup[k] ? 0.f : expf(sc[k] - m);
        sum += sc[k];
    }
    float inv = 1.0f / sum;
    float4 o = make_float4(0.f, 0.f, 0.f, 0.f);
    #pragma unroll
    for (int k = 0; k < MAXK; k++) {
        float wk = sc[k] * inv;
        o.x += wk * rv[k].x;
        o.y += wk * rv[k].y;
        o.z += wk * rv[k].z;
        o.w += wk * rv[k].w;
    }
    half4 h = { (_Float16)o.x, (_Float16)o.y, (_Float16)o.z, (_Float16)o.w };
    *(half4*)&agg[(size_t)i * F + f] = h;
}

// R6-proven 64x64 GEMM tile body, BK=64, 2-buffer LDS = exactly 32KB.
__device__ __forceinline__ void gemm64_body(
    int m0, int n0, int tid, const _Float16* __restrict__ A,
    const _Float16* __restrict__ Bt, float* __restrict__ C,
    int K, int Nc, char* smem) {
    char* AsB = smem;            // [2][64*64] halfs = 16KB
    char* BsB = smem + 16384;    // 16KB
    const int l = tid & 63, wv = tid >> 6;
    const int wm = wv >> 1, wn = wv & 1;
    const int lrow = l & 15, kc = l >> 4;
    const int srow = l >> 3;
    const int sslot = (l & 7) ^ (srow & 7);
    const int nt = K >> 6;
    const int rg0 = wv * 2, rg1 = wv * 2 + 1;
    f32x4 acc[2][2] = {};

    #define GSTAGE(bf, t_)                                                         \
    do {                                                                           \
        int k0_ = (t_) * 64;                                                       \
        gload_lds16(&A[(size_t)(m0 + rg0 * 8 + srow) * K + k0_ + sslot * 8],       \
                    (void*)(AsB + (bf) * 8192 + rg0 * 1024 + l * 16));             \
        gload_lds16(&A[(size_t)(m0 + rg1 * 8 + srow) * K + k0_ + sslot * 8],       \
                    (void*)(AsB + (bf) * 8192 + rg1 * 1024 + l * 16));             \
        gload_lds16(&Bt[(size_t)(n0 + rg0 * 8 + srow) * K + k0_ + sslot * 8],      \
                    (void*)(BsB + (bf) * 8192 + rg0 * 1024 + l * 16));             \
        gload_lds16(&Bt[(size_t)(n0 + rg1 * 8 + srow) * K + k0_ + sslot * 8],      \
                    (void*)(BsB + (bf) * 8192 + rg1 * 1024 + l * 16));             \
    } while (0)

    GSTAGE(0, 0);
    asm volatile("s_waitcnt vmcnt(0)" ::: "memory");
    __syncthreads();

    int buf = 0;
    for (int t = 0; t < nt; ++t) {
        if (t + 1 < nt) GSTAGE(buf ^ 1, t + 1);
        half8 av[2][2], bv[2][2];
        #pragma unroll
        for (int ks = 0; ks < 2; ks++) {
            #pragma unroll
            for (int fq = 0; fq < 2; fq++) {
                int arow = wm * 32 + fq * 16 + lrow;
                int aslot = (ks * 4 + kc) ^ (arow & 7);
                av[ks][fq] = *(const half8*)(AsB + buf * 8192 + arow * 128 + aslot * 16);
                int brow = wn * 32 + fq * 16 + lrow;
                int bslot = (ks * 4 + kc) ^ (brow & 7);
                bv[ks][fq] = *(const half8*)(BsB + buf * 8192 + brow * 128 + bslot * 16);
            }
        }
        #pragma unroll
        for (int ks = 0; ks < 2; ks++)
            #pragma unroll
            for (int fq = 0; fq < 2; fq++)
                #pragma unroll
                for (int g2 = 0; g2 < 2; g2++)
                    acc[fq][g2] = __builtin_amdgcn_mfma_f32_16x16x32_f16(
                        av[ks][fq], bv[ks][g2], acc[fq][g2], 0, 0, 0);
        asm volatile("s_waitcnt vmcnt(0)" ::: "memory");
        __syncthreads();
        buf ^= 1;
    }
    #undef GSTAGE

    #pragma unroll
    for (int fq = 0; fq < 2; fq++)
        #pragma unroll
        for (int g2 = 0; g2 < 2; g2++)
            #pragma unroll
            for (int r = 0; r < 4; r++)
                C[(size_t)(m0 + wm * 32 + fq * 16 + kc * 4 + r) * Nc
                  + n0 + wn * 32 + g2 * 16 + lrow] = acc[fq][g2][r];
}

// ---------------- kernels ----------------

// D1: wa (blocks [0, F/4)) + W->Wt fp16 transpose (rest). R17-proven.
__global__ __launch_bounds__(256) void prep_kernel(
    const float* __restrict__ W, const float* __restrict__ a,
    float* __restrict__ wa, _Float16* __restrict__ Wt, int F) {
    const int tid = threadIdx.x;
    const int nWa = F >> 2;
    if ((int)blockIdx.x >= nWa) {
        __shared__ float t[32][33];
        const int tb = blockIdx.x - nWa;
        const int tpr = F >> 5;
        const int bx = (tb % tpr) * 32;
        const int by = (tb / tpr) * 32;
        const int x = tid & 31, y = tid >> 5;
        for (int i2 = y; i2 < 32; i2 += 8)
            t[i2][x] = W[(size_t)(bx + i2) * F + by + x];
        __syncthreads();
        for (int i2 = y; i2 < 32; i2 += 8)
            Wt[(size_t)(by + i2) * F + bx + x] = (_Float16)t[x][i2];
        return;
    }
    int wave = (int)((blockIdx.x * blockDim.x + tid) >> 6);
    int lane = tid & 63;
    const float4* wr = reinterpret_cast<const float4*>(W + (size_t)wave * F);
    const float4* a1 = reinterpret_cast<const float4*>(a);
    const float4* a2 = reinterpret_cast<const float4*>(a + F);
    float acc1 = 0.f, acc2 = 0.f;
    int F4 = F >> 2;
    for (int c = lane; c < F4; c += 64) {
        float4 w = wr[c];
        acc1 += dot4(w, a1[c]);
        acc2 += dot4(w, a2[c]);
    }
    #pragma unroll
    for (int off = 32; off; off >>= 1) {
        acc1 += __shfl_down(acc1, off);
        acc2 += __shfl_down(acc2, off);
    }
    if (lane == 0) { wa[wave] = acc1; wa[F + wave] = acc2; }
}

// D2: mid rows [0, halfN)
__global__ __launch_bounds__(256) void mid_kernel(
    const float* __restrict__ feat, const float* __restrict__ embed,
    const int* __restrict__ nidx, const float* __restrict__ wa,
    _Float16* __restrict__ agg, int F) {
    __shared__ __align__(16) char smem[192];
    mid_body(blockIdx.x, threadIdx.x, feat, embed, nidx, wa, agg, F, smem);
}

// D3: combo — blocks [0,256): GEMM tiles for m in [0, halfN) (agg rows ready
// via dispatch boundary); blocks [256, 1280): mid rows [halfN, N).
// One 32KB smem shared by branch (mid uses 176B) -> mid co-residency kept.
__global__ __launch_bounds__(256) void combo_kernel(
    const float* __restrict__ feat, const float* __restrict__ embed,
    const int* __restrict__ nidx, const float* __restrict__ wa,
    const _Float16* __restrict__ agg_c, _Float16* __restrict__ agg,
    const _Float16* __restrict__ Wt, float* __restrict__ C, int F, int halfN) {
    __shared__ __align__(16) char smem[32768];
    const int tid = threadIdx.x;
    const int bid = blockIdx.x;
    const int nG = (halfN >> 6) * (F >> 6);       // 16*16 = 256

    if (bid < nG) {
        int cpx = nG >> 3;
        int g = (bid & 7) * cpx + (bid >> 3);     // XCD swizzle (256 % 8 == 0)
        int m0 = (g >> 4) * 64;                   // m in [0, halfN)
        int n0 = (g & 15) * 64;
        gemm64_body(m0, n0, tid, agg_c, Wt, C, F, F, smem);
        return;
    }
    mid_body(halfN + (bid - nG), tid, feat, embed, nidx, wa, agg, F, smem);
}

// D4: remaining GEMM tiles (m in [halfN, N)), R9-proven BK=128 body.
__global__ __launch_bounds__(256) void gemm_f16_kernel(
    const _Float16* __restrict__ A, const _Float16* __restrict__ Bt,
    float* __restrict__ C, int mOff, int N, int K) {
    __shared__ _Float16 As[2][64 * 128];
    __shared__ _Float16 Bs[2][64 * 128];
    const int tid = threadIdx.x;

    int bid = blockIdx.y * gridDim.x + blockIdx.x;
    int nwg = gridDim.x * gridDim.y;
    int cpx = nwg >> 3;                       // nwg % 8 == 0
    int wg = (bid & 7) * cpx + (bid >> 3);
    const int m0 = mOff + (wg / gridDim.x) * 64;
    const int n0 = (wg % gridDim.x) * 64;

    const int l = tid & 63, wv = tid >> 6;
    const int wm = wv >> 1, wn = wv & 1;
    const int lrow = l & 15, kc = l >> 4;
    const int nt = K >> 7;                    // 8

    f32x4 acc[2][2] = {};

    #define STAGE(bf, t)                                                            \
    do {                                                                            \
        int k0_ = (t) * 128;                                                        \
        _Pragma("unroll")                                                           \
        for (int j_ = 0; j_ < 4; j_++) {                                            \
            int u_ = wv * 256 + j_ * 64 + l;                                        \
            int row_ = u_ >> 4, slot_ = (u_ & 15) ^ (row_ & 7);                     \
            gload_lds16(&A[(size_t)(m0 + row_) * K + k0_ + slot_ * 8],              \
                        (void*)((char*)&As[bf][0] + u_ * 16));                      \
        }                                                                           \
        _Pragma("unroll")                                                           \
        for (int j_ = 0; j_ < 4; j_++) {                                            \
            int u_ = wv * 256 + j_ * 64 + l;                                        \
            int row_ = u_ >> 4, slot_ = (u_ & 15) ^ (row_ & 7);                     \
            gload_lds16(&Bt[(size_t)(n0 + row_) * K + k0_ + slot_ * 8],             \
                        (void*)((char*)&Bs[bf][0] + u_ * 16));                      \
        }                                                                           \
    } while (0)

    STAGE(0, 0);

    int buf = 0;
    for (int t = 0; t < nt; ++t) {
        if (t + 1 < nt) {
            STAGE(buf ^ 1, t + 1);
            asm volatile("s_waitcnt vmcnt(8)" ::: "memory");
        } else {
            asm volatile("s_waitcnt vmcnt(0)" ::: "memory");
        }
        __builtin_amdgcn_s_barrier();
        __builtin_amdgcn_sched_barrier(0);

        __builtin_amdgcn_s_setprio(1);
        #pragma unroll
        for (int ks = 0; ks < 4; ks++) {
            half8 av[2], bv[2];
            #pragma unroll
            for (int fq = 0; fq < 2; fq++) {
                int arow = wm * 32 + fq * 16 + lrow;
                int ag = (ks * 4 + kc) ^ (arow & 7);
                av[fq] = *(const half8*)((const char*)&As[buf][0] + arow * 256 + ag * 16);
                int brow = wn * 32 + fq * 16 + lrow;
                int bg = (ks * 4 + kc) ^ (brow & 7);
                bv[fq] = *(const half8*)((const char*)&Bs[buf][0] + brow * 256 + bg * 16);
            }
            #pragma unroll
            for (int fq = 0; fq < 2; fq++)
                #pragma unroll
                for (int g = 0; g < 2; g++)
                    acc[fq][g] = __builtin_amdgcn_mfma_f32_16x16x32_f16(
                        av[fq], bv[g], acc[fq][g], 0, 0, 0);
        }
        __builtin_amdgcn_s_setprio(0);

        __builtin_amdgcn_sched_barrier(0);
        __builtin_amdgcn_s_barrier();
        buf ^= 1;
    }
    #undef STAGE

    #pragma unroll
    for (int fq = 0; fq < 2; fq++)
        #pragma unroll
        for (int g = 0; g < 2; g++)
            #pragma unroll
            for (int r = 0; r < 4; r++)
                C[(size_t)(m0 + wm * 32 + fq * 16 + kc * 4 + r) * N
                  + n0 + wn * 32 + g * 16 + lrow] = acc[fq][g][r];
}

extern "C" void kernel_launch(void* const* d_in, const int* in_sizes, int n_in,
                              void* d_out, int out_size, void* d_ws, size_t ws_size,
                              hipStream_t stream) {
    const float* feat  = (const float*)d_in[0];
    const float* embed = (const float*)d_in[1];
    const float* W     = (const float*)d_in[2];
    const float* a     = (const float*)d_in[3];
    const int*   nidx  = (const int*)d_in[4];

    int F = in_sizes[3] / 2;          // 1024
    int N = in_sizes[0] / F;          // 2048
    int M = in_sizes[1] / F;          // 8192
    int halfN = N / 2;                // 1024

    float* ws = (float*)d_ws;
    float* wa = ws;                                 // 2F floats
    _Float16* agg_f16 = (_Float16*)(wa + 2 * F);    // N*F halfs
    _Float16* wt_f16  = agg_f16 + (size_t)N * F;    // F*F halfs
    float* C = (float*)d_out;
    (void)M;

    // D1: wa + W->Wt transpose
    {
        int nWa = F / 4;
        int nT  = (F / 32) * (F / 32);
        prep_kernel<<<nWa + nT, 256, 0, stream>>>(W, a, wa, wt_f16, F);
    }
    // D2: mid rows [0, halfN)
    mid_kernel<<<halfN, 256, 0, stream>>>(feat, embed, nidx, wa, agg_f16, F);
    // D3: combo — gemm(m < halfN) + mid rows [halfN, N)
    {
        int nG = (halfN / 64) * (F / 64);           // 256
        combo_kernel<<<nG + halfN, 256, 0, stream>>>(feat, embed, nidx, wa,
                                                     agg_f16, agg_f16, wt_f16,
                                                     C, F, halfN);
    }
    // D4: gemm(m >= halfN), BK=128
    {
        dim3 grid(F / 64, halfN / 64);              // (16, 16) = 256 tiles
        gemm_f16_kernel<<<grid, 256, 0, stream>>>(agg_f16, wt_f16, C, halfN, F, F);
    }
}

// Round 19
// 38.302 us; speedup vs baseline: 1.1562x; 1.1562x over previous
//
#include <hip/hip_runtime.h>
#include <math.h>

#define ALPHA 0.2f
#define MAXK 10

typedef _Float16 half8 __attribute__((ext_vector_type(8)));
typedef _Float16 half4 __attribute__((ext_vector_type(4)));
typedef float f32x4 __attribute__((ext_vector_type(4)));

__device__ __forceinline__ void gload_lds16(const void* g, void* l) {
    __builtin_amdgcn_global_load_lds(
        (const __attribute__((address_space(1))) unsigned int*)g,
        (__attribute__((address_space(3))) unsigned int*)l, 16, 0, 0);
}

__device__ __forceinline__ float dot4(float4 a, float4 b) {
    return a.x * b.x + a.y * b.y + a.z * b.z + a.w * b.w;
}

// D1: blocks [0, F/4): wa = W @ [a1,a2] (one wave per W row);
//     blocks [F/4, F/4 + (F/32)^2): W->Wt fp16 transpose;
//     blocks [F/4 + (F/32)^2, + M/4): embed fp32 -> fp16 conversion.
// All three are independent (read-only inputs W/a/embed); the conversion's
// 48MB streams through D1's idle HBM capacity and halves mid's gather bytes.
__global__ __launch_bounds__(256) void prep_kernel(
    const float* __restrict__ W, const float* __restrict__ a,
    const float* __restrict__ embed, float* __restrict__ wa,
    _Float16* __restrict__ Wt, _Float16* __restrict__ embed16, int F, int M) {
    const int tid = threadIdx.x;
    const int nWa = F >> 2;                       // 256
    const int nT  = (F >> 5) * (F >> 5);          // 1024

    if ((int)blockIdx.x >= nWa + nT) {
        // ---- embed conversion: 4 rows (4096 elems = 1024 float4) per block ----
        const int cb = blockIdx.x - nWa - nT;     // [0, M/4)
        const float4* e4 = reinterpret_cast<const float4*>(embed);
        size_t base = (size_t)cb * 1024;          // float4-chunk base
        #pragma unroll
        for (int j = 0; j < 4; j++) {
            size_t c = base + j * 256 + tid;
            float4 v = e4[c];
            half4 h = { (_Float16)v.x, (_Float16)v.y, (_Float16)v.z, (_Float16)v.w };
            *(half4*)&embed16[c * 4] = h;
        }
        return;
    }

    if ((int)blockIdx.x >= nWa) {
        // ---- transpose: Wt[n][k] = (fp16) W[k][n], 32x32 tiles ----
        __shared__ float t[32][33];
        const int tb = blockIdx.x - nWa;
        const int tpr = F >> 5;
        const int bx = (tb % tpr) * 32;
        const int by = (tb / tpr) * 32;
        const int x = tid & 31, y = tid >> 5;
        for (int i2 = y; i2 < 32; i2 += 8)
            t[i2][x] = W[(size_t)(bx + i2) * F + by + x];
        __syncthreads();
        for (int i2 = y; i2 < 32; i2 += 8)
            Wt[(size_t)(by + i2) * F + bx + x] = (_Float16)t[x][i2];
        return;
    }

    // ---- wa: one wave per W row ----
    int wave = (int)((blockIdx.x * blockDim.x + tid) >> 6);
    int lane = tid & 63;
    const float4* wr = reinterpret_cast<const float4*>(W + (size_t)wave * F);
    const float4* a1 = reinterpret_cast<const float4*>(a);
    const float4* a2 = reinterpret_cast<const float4*>(a + F);
    float acc1 = 0.f, acc2 = 0.f;
    int F4 = F >> 2;
    for (int c = lane; c < F4; c += 64) {
        float4 w = wr[c];
        acc1 += dot4(w, a1[c]);
        acc2 += dot4(w, a2[c]);
    }
    #pragma unroll
    for (int off = 32; off; off >>= 1) {
        acc1 += __shfl_down(acc1, off);
        acc2 += __shfl_down(acc2, off);
    }
    if (lane == 0) { wa[wave] = acc1; wa[F + wave] = acc2; }
}

// D2: aggregate, one block per output row. Gathers fp16 embed rows (8B/lane
// half4 loads — halves the bottleneck-tier traffic vs fp32).
__global__ __launch_bounds__(256) void mid_kernel(
    const float* __restrict__ feat, const _Float16* __restrict__ embed16,
    const int* __restrict__ nidx, const float* __restrict__ wa,
    _Float16* __restrict__ agg, int F) {
    const int tid = threadIdx.x;
    const int i = blockIdx.x;
    const int f = tid * 4;

    int idx[MAXK];
    bool dup[MAXK];
    #pragma unroll
    for (int k = 0; k < MAXK; k++) idx[k] = nidx[i * MAXK + k];
    #pragma unroll
    for (int k = 0; k < MAXK; k++) {
        bool d = false;
        #pragma unroll
        for (int p = 0; p < MAXK; p++)
            if (p < k) d |= (idx[p] == idx[k]);
        dup[k] = d;
    }

    float4 wa1 = *(const float4*)&wa[f];
    float4 wa2 = *(const float4*)&wa[F + f];
    float4 fv  = *(const float4*)&feat[(size_t)i * F + f];
    float a1p = dot4(fv, wa1);

    half4 rv[MAXK];                 // fp16 row cache: 20 VGPRs
    float a2p[MAXK];
    #pragma unroll
    for (int k = 0; k < MAXK; k++) {
        rv[k] = *(const half4*)&embed16[(size_t)idx[k] * F + f];
        a2p[k] = (float)rv[k][0] * wa2.x + (float)rv[k][1] * wa2.y
               + (float)rv[k][2] * wa2.z + (float)rv[k][3] * wa2.w;
    }

    #pragma unroll
    for (int off = 32; off; off >>= 1) {
        a1p += __shfl_down(a1p, off);
        #pragma unroll
        for (int k = 0; k < MAXK; k++) a2p[k] += __shfl_down(a2p[k], off);
    }
    __shared__ float red[MAXK + 1][4];
    const int w = tid >> 6, l = tid & 63;
    if (l == 0) {
        red[0][w] = a1p;
        #pragma unroll
        for (int k = 0; k < MAXK; k++) red[k + 1][w] = a2p[k];
    }
    __syncthreads();

    float s1 = red[0][0] + red[0][1] + red[0][2] + red[0][3];
    float sc[MAXK];
    float m = -INFINITY;
    #pragma unroll
    for (int k = 0; k < MAXK; k++) {
        float v = s1 + red[k + 1][0] + red[k + 1][1] + red[k + 1][2] + red[k + 1][3];
        v = v > 0.f ? v : ALPHA * v;
        sc[k] = v;
        if (!dup[k]) m = fmaxf(m, v);
    }
    float sum = 0.f;
    #pragma unroll
    for (int k = 0; k < MAXK; k++) {
        sc[k] = dup[k] ? 0.f : expf(sc[k] - m);
        sum += sc[k];
    }
    float inv = 1.0f / sum;

    float4 o = make_float4(0.f, 0.f, 0.f, 0.f);
    #pragma unroll
    for (int k = 0; k < MAXK; k++) {
        float wk = sc[k] * inv;
        o.x += wk * (float)rv[k][0];
        o.y += wk * (float)rv[k][1];
        o.z += wk * (float)rv[k][2];
        o.w += wk * (float)rv[k][3];
    }
    half4 h = { (_Float16)o.x, (_Float16)o.y, (_Float16)o.z, (_Float16)o.w };
    *(half4*)&agg[(size_t)i * F + f] = h;
}

// D3: C = A @ Bt^T — EXACT R9/R17 config (best known): 64x64 tile, BK=128,
// 4 waves, 2-buffer LDS, counted vmcnt(8) + raw s_barrier, rule-21 swizzle,
// setprio, bijective XCD swizzle.
__global__ __launch_bounds__(256) void gemm_f16_kernel(
    const _Float16* __restrict__ A, const _Float16* __restrict__ Bt,
    float* __restrict__ C, int M, int N, int K) {
    __shared__ _Float16 As[2][64 * 128];
    __shared__ _Float16 Bs[2][64 * 128];
    const int tid = threadIdx.x;

    int bid = blockIdx.y * gridDim.x + blockIdx.x;
    int nwg = gridDim.x * gridDim.y;
    int cpx = nwg >> 3;                       // nwg % 8 == 0
    int wg = (bid & 7) * cpx + (bid >> 3);
    const int m0 = (wg / gridDim.x) * 64;
    const int n0 = (wg % gridDim.x) * 64;

    const int l = tid & 63, wv = tid >> 6;
    const int wm = wv >> 1, wn = wv & 1;
    const int lrow = l & 15, kc = l >> 4;
    const int nt = K >> 7;                    // 8

    f32x4 acc[2][2] = {};

    #define STAGE(bf, t)                                                            \
    do {                                                                            \
        int k0_ = (t) * 128;                                                        \
        _Pragma("unroll")                                                           \
        for (int j_ = 0; j_ < 4; j_++) {                                            \
            int u_ = wv * 256 + j_ * 64 + l;                                        \
            int row_ = u_ >> 4, slot_ = (u_ & 15) ^ (row_ & 7);                     \
            gload_lds16(&A[(size_t)(m0 + row_) * K + k0_ + slot_ * 8],              \
                        (void*)((char*)&As[bf][0] + u_ * 16));                      \
        }                                                                           \
        _Pragma("unroll")                                                           \
        for (int j_ = 0; j_ < 4; j_++) {                                            \
            int u_ = wv * 256 + j_ * 64 + l;                                        \
            int row_ = u_ >> 4, slot_ = (u_ & 15) ^ (row_ & 7);                     \
            gload_lds16(&Bt[(size_t)(n0 + row_) * K + k0_ + slot_ * 8],             \
                        (void*)((char*)&Bs[bf][0] + u_ * 16));                      \
        }                                                                           \
    } while (0)

    STAGE(0, 0);

    int buf = 0;
    for (int t = 0; t < nt; ++t) {
        if (t + 1 < nt) {
            STAGE(buf ^ 1, t + 1);
            asm volatile("s_waitcnt vmcnt(8)" ::: "memory");   // stage-t landed
        } else {
            asm volatile("s_waitcnt vmcnt(0)" ::: "memory");
        }
        __builtin_amdgcn_s_barrier();          // raw: no vmcnt(0) drain
        __builtin_amdgcn_sched_barrier(0);

        __builtin_amdgcn_s_setprio(1);
        #pragma unroll
        for (int ks = 0; ks < 4; ks++) {       // 4 x K=32 chunks (BK=128)
            half8 av[2], bv[2];
            #pragma unroll
            for (int fq = 0; fq < 2; fq++) {
                int arow = wm * 32 + fq * 16 + lrow;
                int ag = (ks * 4 + kc) ^ (arow & 7);
                av[fq] = *(const half8*)((const char*)&As[buf][0] + arow * 256 + ag * 16);
                int brow = wn * 32 + fq * 16 + lrow;
                int bg = (ks * 4 + kc) ^ (brow & 7);
                bv[fq] = *(const half8*)((const char*)&Bs[buf][0] + brow * 256 + bg * 16);
            }
            #pragma unroll
            for (int fq = 0; fq < 2; fq++)
                #pragma unroll
                for (int g = 0; g < 2; g++)
                    acc[fq][g] = __builtin_amdgcn_mfma_f32_16x16x32_f16(
                        av[fq], bv[g], acc[fq][g], 0, 0, 0);
        }
        __builtin_amdgcn_s_setprio(0);

        __builtin_amdgcn_sched_barrier(0);     // keep consumes before close
        __builtin_amdgcn_s_barrier();
        buf ^= 1;
    }
    #undef STAGE

    // C/D layout: col = lane&15 (=lrow), row = (lane>>4)*4 + r (=kc*4+r)
    #pragma unroll
    for (int fq = 0; fq < 2; fq++)
        #pragma unroll
        for (int g = 0; g < 2; g++)
            #pragma unroll
            for (int r = 0; r < 4; r++)
                C[(size_t)(m0 + wm * 32 + fq * 16 + kc * 4 + r) * N
                  + n0 + wn * 32 + g * 16 + lrow] = acc[fq][g][r];
}

extern "C" void kernel_launch(void* const* d_in, const int* in_sizes, int n_in,
                              void* d_out, int out_size, void* d_ws, size_t ws_size,
                              hipStream_t stream) {
    const float* feat  = (const float*)d_in[0];
    const float* embed = (const float*)d_in[1];
    const float* W     = (const float*)d_in[2];
    const float* a     = (const float*)d_in[3];
    const int*   nidx  = (const int*)d_in[4];

    int F = in_sizes[3] / 2;          // 1024
    int N = in_sizes[0] / F;          // 2048
    int M = in_sizes[1] / F;          // 8192

    float* ws = (float*)d_ws;
    float* wa = ws;                                       // 2F floats
    _Float16* agg_f16 = (_Float16*)(wa + 2 * F);          // N*F halfs
    _Float16* wt_f16  = agg_f16 + (size_t)N * F;          // F*F halfs
    _Float16* emb16   = wt_f16 + (size_t)F * F;           // M*F halfs (16MB)

    // D1: wa + W->Wt transpose + embed fp32->fp16 conversion
    {
        int nWa = F / 4;                                  // 256
        int nT  = (F / 32) * (F / 32);                    // 1024
        int nC  = M / 4;                                  // 2048
        prep_kernel<<<nWa + nT + nC, 256, 0, stream>>>(W, a, embed, wa,
                                                       wt_f16, emb16, F, M);
    }
    // D2: aggregate (fp16 gather)
    mid_kernel<<<N, 256, 0, stream>>>(feat, emb16, nidx, wa, agg_f16, F);
    // D3: out = agg @ W via MFMA
    {
        dim3 grid(F / 64, N / 64);                        // (16, 32) = 512
        gemm_f16_kernel<<<grid, 256, 0, stream>>>(agg_f16, wt_f16, (float*)d_out, N, F, F);
    }
}

// Round 20
// 37.544 us; speedup vs baseline: 1.1796x; 1.0202x over previous
//
#include <hip/hip_runtime.h>
#include <math.h>

#define ALPHA 0.2f
#define MAXK 10

typedef _Float16 half8 __attribute__((ext_vector_type(8)));
typedef _Float16 half4 __attribute__((ext_vector_type(4)));
typedef float f32x4 __attribute__((ext_vector_type(4)));

__device__ __forceinline__ void gload_lds16(const void* g, void* l) {
    __builtin_amdgcn_global_load_lds(
        (const __attribute__((address_space(1))) unsigned int*)g,
        (__attribute__((address_space(3))) unsigned int*)l, 16, 0, 0);
}

__device__ __forceinline__ float dot4(float4 a, float4 b) {
    return a.x * b.x + a.y * b.y + a.z * b.z + a.w * b.w;
}

// D1: blocks [0, F/4): wa = W @ [a1,a2]; blocks [F/4, +1024): W->Wt fp16
// transpose; rest: embed fp32 -> fp16 conversion (48MB stream rides D1).
__global__ __launch_bounds__(256) void prep_kernel(
    const float* __restrict__ W, const float* __restrict__ a,
    const float* __restrict__ embed, float* __restrict__ wa,
    _Float16* __restrict__ Wt, _Float16* __restrict__ embed16, int F, int M) {
    const int tid = threadIdx.x;
    const int nWa = F >> 2;                       // 256
    const int nT  = (F >> 5) * (F >> 5);          // 1024

    if ((int)blockIdx.x >= nWa + nT) {
        // ---- embed conversion: 4 rows per block ----
        const int cb = blockIdx.x - nWa - nT;     // [0, M/4)
        const float4* e4 = reinterpret_cast<const float4*>(embed);
        size_t base = (size_t)cb * 1024;
        #pragma unroll
        for (int j = 0; j < 4; j++) {
            size_t c = base + j * 256 + tid;
            float4 v = e4[c];
            half4 h = { (_Float16)v.x, (_Float16)v.y, (_Float16)v.z, (_Float16)v.w };
            *(half4*)&embed16[c * 4] = h;
        }
        return;
    }

    if ((int)blockIdx.x >= nWa) {
        // ---- transpose: Wt[n][k] = (fp16) W[k][n], 32x32 tiles ----
        __shared__ float t[32][33];
        const int tb = blockIdx.x - nWa;
        const int tpr = F >> 5;
        const int bx = (tb % tpr) * 32;
        const int by = (tb / tpr) * 32;
        const int x = tid & 31, y = tid >> 5;
        for (int i2 = y; i2 < 32; i2 += 8)
            t[i2][x] = W[(size_t)(bx + i2) * F + by + x];
        __syncthreads();
        for (int i2 = y; i2 < 32; i2 += 8)
            Wt[(size_t)(by + i2) * F + bx + x] = (_Float16)t[x][i2];
        return;
    }

    // ---- wa: one wave per W row ----
    int wave = (int)((blockIdx.x * blockDim.x + tid) >> 6);
    int lane = tid & 63;
    const float4* wr = reinterpret_cast<const float4*>(W + (size_t)wave * F);
    const float4* a1 = reinterpret_cast<const float4*>(a);
    const float4* a2 = reinterpret_cast<const float4*>(a + F);
    float acc1 = 0.f, acc2 = 0.f;
    int F4 = F >> 2;
    for (int c = lane; c < F4; c += 64) {
        float4 w = wr[c];
        acc1 += dot4(w, a1[c]);
        acc2 += dot4(w, a2[c]);
    }
    #pragma unroll
    for (int off = 32; off; off >>= 1) {
        acc1 += __shfl_down(acc1, off);
        acc2 += __shfl_down(acc2, off);
    }
    if (lane == 0) { wa[wave] = acc1; wa[F + wave] = acc2; }
}

// D2: aggregate, TWO rows per block (threads 0-127 -> row 2b, 128-255 ->
// row 2b+1). fp16 gather as half8 = 16B/lane -> 1KB/wave fully coalesced,
// HALVING total gather instructions vs R17/R19 (the request-latency lever).
// Row groups = whole waves, so shuffle reduces never cross rows.
__global__ __launch_bounds__(256) void mid_kernel(
    const float* __restrict__ feat, const _Float16* __restrict__ embed16,
    const int* __restrict__ nidx, const float* __restrict__ wa,
    _Float16* __restrict__ agg, int F) {
    const int tid = threadIdx.x;
    const int rowSel = tid >> 7;            // 0 or 1
    const int t = tid & 127;
    const int i = (blockIdx.x << 1) | rowSel;
    const int f = t * 8;                    // element offset (8 per thread)

    int idx[MAXK];
    bool dup[MAXK];
    #pragma unroll
    for (int k = 0; k < MAXK; k++) idx[k] = nidx[i * MAXK + k];
    #pragma unroll
    for (int k = 0; k < MAXK; k++) {
        bool d = false;
        #pragma unroll
        for (int p = 0; p < MAXK; p++)
            if (p < k) d |= (idx[p] == idx[k]);
        dup[k] = d;
    }

    float4 w1a = *(const float4*)&wa[f];
    float4 w1b = *(const float4*)&wa[f + 4];
    float4 w2a = *(const float4*)&wa[F + f];
    float4 w2b = *(const float4*)&wa[F + f + 4];
    float4 fva = *(const float4*)&feat[(size_t)i * F + f];
    float4 fvb = *(const float4*)&feat[(size_t)i * F + f + 4];
    float a1p = dot4(fva, w1a) + dot4(fvb, w1b);

    half8 rv[MAXK];                         // 40 VGPRs
    float a2p[MAXK];
    #pragma unroll
    for (int k = 0; k < MAXK; k++) {
        rv[k] = *(const half8*)&embed16[(size_t)idx[k] * F + f];
        a2p[k] = (float)rv[k][0] * w2a.x + (float)rv[k][1] * w2a.y
               + (float)rv[k][2] * w2a.z + (float)rv[k][3] * w2a.w
               + (float)rv[k][4] * w2b.x + (float)rv[k][5] * w2b.y
               + (float)rv[k][6] * w2b.z + (float)rv[k][7] * w2b.w;
    }

    // within-wave butterfly (waves are row-pure), then 2-slot LDS combine
    #pragma unroll
    for (int off = 32; off; off >>= 1) {
        a1p += __shfl_xor(a1p, off);
        #pragma unroll
        for (int k = 0; k < MAXK; k++) a2p[k] += __shfl_xor(a2p[k], off);
    }
    __shared__ float red[MAXK + 1][4];
    const int w = tid >> 6;                 // wave slot 0..3
    if ((tid & 63) == 0) {
        red[0][w] = a1p;
        #pragma unroll
        for (int k = 0; k < MAXK; k++) red[k + 1][w] = a2p[k];
    }
    __syncthreads();

    const int wb = rowSel * 2;              // this row's wave slots
    float s1 = red[0][wb] + red[0][wb + 1];
    float sc[MAXK];
    float m = -INFINITY;
    #pragma unroll
    for (int k = 0; k < MAXK; k++) {
        float v = s1 + red[k + 1][wb] + red[k + 1][wb + 1];
        v = v > 0.f ? v : ALPHA * v;
        sc[k] = v;
        if (!dup[k]) m = fmaxf(m, v);
    }
    float sum = 0.f;
    #pragma unroll
    for (int k = 0; k < MAXK; k++) {
        sc[k] = dup[k] ? 0.f : expf(sc[k] - m);
        sum += sc[k];
    }
    float inv = 1.0f / sum;

    float o[8] = {};
    #pragma unroll
    for (int k = 0; k < MAXK; k++) {
        float wk = sc[k] * inv;
        #pragma unroll
        for (int j = 0; j < 8; j++) o[j] += wk * (float)rv[k][j];
    }
    half8 ho;
    #pragma unroll
    for (int j = 0; j < 8; j++) ho[j] = (_Float16)o[j];
    *(half8*)&agg[(size_t)i * F + f] = ho;
}

// D3: C = A @ Bt^T — EXACT R9/R17 config (best known): 64x64 tile, BK=128,
// 4 waves, 2-buffer LDS, counted vmcnt(8) + raw s_barrier, rule-21 swizzle,
// setprio, bijective XCD swizzle.
__global__ __launch_bounds__(256) void gemm_f16_kernel(
    const _Float16* __restrict__ A, const _Float16* __restrict__ Bt,
    float* __restrict__ C, int M, int N, int K) {
    __shared__ _Float16 As[2][64 * 128];
    __shared__ _Float16 Bs[2][64 * 128];
    const int tid = threadIdx.x;

    int bid = blockIdx.y * gridDim.x + blockIdx.x;
    int nwg = gridDim.x * gridDim.y;
    int cpx = nwg >> 3;                       // nwg % 8 == 0
    int wg = (bid & 7) * cpx + (bid >> 3);
    const int m0 = (wg / gridDim.x) * 64;
    const int n0 = (wg % gridDim.x) * 64;

    const int l = tid & 63, wv = tid >> 6;
    const int wm = wv >> 1, wn = wv & 1;
    const int lrow = l & 15, kc = l >> 4;
    const int nt = K >> 7;                    // 8

    f32x4 acc[2][2] = {};

    #define STAGE(bf, t)                                                            \
    do {                                                                            \
        int k0_ = (t) * 128;                                                        \
        _Pragma("unroll")                                                           \
        for (int j_ = 0; j_ < 4; j_++) {                                            \
            int u_ = wv * 256 + j_ * 64 + l;                                        \
            int row_ = u_ >> 4, slot_ = (u_ & 15) ^ (row_ & 7);                     \
            gload_lds16(&A[(size_t)(m0 + row_) * K + k0_ + slot_ * 8],              \
                        (void*)((char*)&As[bf][0] + u_ * 16));                      \
        }                                                                           \
        _Pragma("unroll")                                                           \
        for (int j_ = 0; j_ < 4; j_++) {                                            \
            int u_ = wv * 256 + j_ * 64 + l;                                        \
            int row_ = u_ >> 4, slot_ = (u_ & 15) ^ (row_ & 7);                     \
            gload_lds16(&Bt[(size_t)(n0 + row_) * K + k0_ + slot_ * 8],             \
                        (void*)((char*)&Bs[bf][0] + u_ * 16));                      \
        }                                                                           \
    } while (0)

    STAGE(0, 0);

    int buf = 0;
    for (int t = 0; t < nt; ++t) {
        if (t + 1 < nt) {
            STAGE(buf ^ 1, t + 1);
            asm volatile("s_waitcnt vmcnt(8)" ::: "memory");   // stage-t landed
        } else {
            asm volatile("s_waitcnt vmcnt(0)" ::: "memory");
        }
        __builtin_amdgcn_s_barrier();          // raw: no vmcnt(0) drain
        __builtin_amdgcn_sched_barrier(0);

        __builtin_amdgcn_s_setprio(1);
        #pragma unroll
        for (int ks = 0; ks < 4; ks++) {       // 4 x K=32 chunks (BK=128)
            half8 av[2], bv[2];
            #pragma unroll
            for (int fq = 0; fq < 2; fq++) {
                int arow = wm * 32 + fq * 16 + lrow;
                int ag = (ks * 4 + kc) ^ (arow & 7);
                av[fq] = *(const half8*)((const char*)&As[buf][0] + arow * 256 + ag * 16);
                int brow = wn * 32 + fq * 16 + lrow;
                int bg = (ks * 4 + kc) ^ (brow & 7);
                bv[fq] = *(const half8*)((const char*)&Bs[buf][0] + brow * 256 + bg * 16);
            }
            #pragma unroll
            for (int fq = 0; fq < 2; fq++)
                #pragma unroll
                for (int g = 0; g < 2; g++)
                    acc[fq][g] = __builtin_amdgcn_mfma_f32_16x16x32_f16(
                        av[fq], bv[g], acc[fq][g], 0, 0, 0);
        }
        __builtin_amdgcn_s_setprio(0);

        __builtin_amdgcn_sched_barrier(0);     // keep consumes before close
        __builtin_amdgcn_s_barrier();
        buf ^= 1;
    }
    #undef STAGE

    // C/D layout: col = lane&15 (=lrow), row = (lane>>4)*4 + r (=kc*4+r)
    #pragma unroll
    for (int fq = 0; fq < 2; fq++)
        #pragma unroll
        for (int g = 0; g < 2; g++)
            #pragma unroll
            for (int r = 0; r < 4; r++)
                C[(size_t)(m0 + wm * 32 + fq * 16 + kc * 4 + r) * N
                  + n0 + wn * 32 + g * 16 + lrow] = acc[fq][g][r];
}

extern "C" void kernel_launch(void* const* d_in, const int* in_sizes, int n_in,
                              void* d_out, int out_size, void* d_ws, size_t ws_size,
                              hipStream_t stream) {
    const float* feat  = (const float*)d_in[0];
    const float* embed = (const float*)d_in[1];
    const float* W     = (const float*)d_in[2];
    const float* a     = (const float*)d_in[3];
    const int*   nidx  = (const int*)d_in[4];

    int F = in_sizes[3] / 2;          // 1024
    int N = in_sizes[0] / F;          // 2048
    int M = in_sizes[1] / F;          // 8192

    float* ws = (float*)d_ws;
    float* wa = ws;                                       // 2F floats
    _Float16* agg_f16 = (_Float16*)(wa + 2 * F);          // N*F halfs
    _Float16* wt_f16  = agg_f16 + (size_t)N * F;          // F*F halfs
    _Float16* emb16   = wt_f16 + (size_t)F * F;           // M*F halfs (16MB)

    // D1: wa + W->Wt transpose + embed fp32->fp16 conversion
    {
        int nWa = F / 4;                                  // 256
        int nT  = (F / 32) * (F / 32);                    // 1024
        int nC  = M / 4;                                  // 2048
        prep_kernel<<<nWa + nT + nC, 256, 0, stream>>>(W, a, embed, wa,
                                                       wt_f16, emb16, F, M);
    }
    // D2: aggregate — 2 rows/block, half8 gather (half the requests)
    mid_kernel<<<N / 2, 256, 0, stream>>>(feat, emb16, nidx, wa, agg_f16, F);
    // D3: out = agg @ W via MFMA
    {
        dim3 grid(F / 64, N / 64);                        // (16, 32) = 512
        gemm_f16_kernel<<<grid, 256, 0, stream>>>(agg_f16, wt_f16, (float*)d_out, N, F, F);
    }
}